// Round 6
// baseline (1830.253 us; speedup 1.0000x reference)
//
#include <hip/hip_runtime.h>
#include <hip/hip_bf16.h>
#include <math.h>

typedef __bf16 bf16_t;
typedef __bf16 bf16x8 __attribute__((ext_vector_type(8)));
typedef __bf16 bf16x4 __attribute__((ext_vector_type(4)));
typedef float f32x4 __attribute__((ext_vector_type(4)));
typedef float f32x16 __attribute__((ext_vector_type(16)));
typedef unsigned short u16;
typedef unsigned int u32;
typedef u16 u16x8 __attribute__((ext_vector_type(8)));
typedef u32 u32x4 __attribute__((ext_vector_type(4)));

#define NDEPTH 4
#define DIM 1024
#define NHEADS 16
#define MLP_DIM 4096
#define CTXD 768
#define NTOK 4096
#define NCTX 2048
// softmax in exp2 domain: p = 2^(s*SC2 - m2), SC2 = 0.125 * log2(e)
#define ATT_SC2 0.18033688011112042f

__device__ inline void gload_lds16(const void* g, void* l) {
  __builtin_amdgcn_global_load_lds(
      (const __attribute__((address_space(1))) void*)g,
      (__attribute__((address_space(3))) void*)l, 16, 0, 0);
}

__device__ inline u32 packbf2(float a, float b) {
  union { bf16_t h[2]; u32 w; } u;
  u.h[0] = (bf16_t)a; u.h[1] = (bf16_t)b;
  return u.w;
}

// Shared epilogue: EPI 0 = bf16 out; 2 = bias+GELU bf16; 3 = bias+residual f32.
template<int EPI>
__device__ inline void epi_store(void* outp, const float* bias, const float* res,
                                 int row, int col, int N, float v) {
  size_t idx = (size_t)row * N + col;
  if (EPI == 3) {
    ((float*)outp)[idx] = v + bias[col] + res[idx];
  } else if (EPI == 2) {
    float vb = v + bias[col];
    ((bf16_t*)outp)[idx] = (bf16_t)(0.5f * vb * (1.f + erff(vb * 0.70710678118f)));
  } else {
    ((bf16_t*)outp)[idx] = (bf16_t)v;
  }
}

// ---------------- GEMM 128x128 tile, 512 thr (8 waves 2x4, per-wave 64x32) ----
template<int EPI>
__global__ __launch_bounds__(512) void gemm_bf16(
    const bf16_t* __restrict__ A, const bf16_t* __restrict__ Bt,
    const float* __restrict__ bias, const float* __restrict__ res,
    void* __restrict__ outp, int M, int N, int K)
{
  __shared__ alignas(16) bf16_t As[3][128 * 32];
  __shared__ alignas(16) bf16_t Bs[3][128 * 32];
  const int tid = threadIdx.x, lane = tid & 63, wave = tid >> 6;
  const int bx = blockIdx.x, by = blockIdx.y;
  const int wr = wave >> 2, wc = wave & 3;
  const int l15 = lane & 15, l4 = lane >> 4;

  const bf16_t* Ag = A + (size_t)by * 128 * K;
  const bf16_t* Bg = Bt + (size_t)bx * 128 * K;

  f32x4 acc[4][2] = {};

  const int srow = tid >> 2, soff = (tid & 3) * 8;
  auto stage = [&](int buf, int k0) {
    gload_lds16(Ag + (size_t)srow * K + k0 + soff, &As[buf][(size_t)tid * 8]);
    gload_lds16(Bg + (size_t)srow * K + k0 + soff, &Bs[buf][(size_t)tid * 8]);
  };

  const int nk = K >> 5;
  stage(0, 0);
  stage(1, 32);
  asm volatile("s_waitcnt vmcnt(2)" ::: "memory");
  __builtin_amdgcn_s_barrier();
  __builtin_amdgcn_sched_barrier(0);

  for (int t = 0; t < nk; ++t) {
    const int cur = t % 3;
    if (t + 2 < nk) stage((t + 2) % 3, (t + 2) << 5);

    bf16x8 af[4], bfr[2];
#pragma unroll
    for (int mi = 0; mi < 4; ++mi)
      af[mi] = *(const bf16x8*)&As[cur][(wr * 64 + mi * 16 + l15) * 32 + l4 * 8];
#pragma unroll
    for (int ni = 0; ni < 2; ++ni)
      bfr[ni] = *(const bf16x8*)&Bs[cur][(wc * 32 + ni * 16 + l15) * 32 + l4 * 8];
#pragma unroll
    for (int mi = 0; mi < 4; ++mi)
#pragma unroll
      for (int ni = 0; ni < 2; ++ni)
        acc[mi][ni] = __builtin_amdgcn_mfma_f32_16x16x32_bf16(af[mi], bfr[ni], acc[mi][ni], 0, 0, 0);

    if (t + 2 < nk) {
      asm volatile("s_waitcnt vmcnt(2)" ::: "memory");
    } else if (t + 1 < nk) {
      asm volatile("s_waitcnt vmcnt(0)" ::: "memory");
    } else {
      break;
    }
    __builtin_amdgcn_s_barrier();
    __builtin_amdgcn_sched_barrier(0);
  }

  const int r0 = by * 128 + wr * 64, c0 = bx * 128 + wc * 32;
#pragma unroll
  for (int ni = 0; ni < 2; ++ni)
#pragma unroll
    for (int mi = 0; mi < 4; ++mi)
#pragma unroll
      for (int r = 0; r < 4; ++r)
        epi_store<EPI>(outp, bias, res, r0 + mi * 16 + l4 * 4 + r,
                       c0 + ni * 16 + l15, N, acc[mi][ni][r]);
}

// ---------------- GEMM 64x64 tile, 256 thr (4 waves 2x2, per-wave 32x32) -----
template<int EPI>
__global__ __launch_bounds__(256) void gemm64_bf16(
    const bf16_t* __restrict__ A, const bf16_t* __restrict__ Bt,
    const float* __restrict__ bias, const float* __restrict__ res,
    void* __restrict__ outp, int M, int N, int K)
{
  __shared__ alignas(16) bf16_t As[3][64 * 32];
  __shared__ alignas(16) bf16_t Bs[3][64 * 32];
  const int tid = threadIdx.x, lane = tid & 63, wave = tid >> 6;
  const int bx = blockIdx.x, by = blockIdx.y;
  const int wr = wave >> 1, wc = wave & 1;
  const int l15 = lane & 15, l4 = lane >> 4;

  const bf16_t* Ag = A + (size_t)by * 64 * K;
  const bf16_t* Bg = Bt + (size_t)bx * 64 * K;

  f32x4 acc[2][2] = {};

  const int srow = tid >> 2, soff = (tid & 3) * 8;
  auto stage = [&](int buf, int k0) {
    gload_lds16(Ag + (size_t)srow * K + k0 + soff, &As[buf][(size_t)tid * 8]);
    gload_lds16(Bg + (size_t)srow * K + k0 + soff, &Bs[buf][(size_t)tid * 8]);
  };

  const int nk = K >> 5;
  stage(0, 0);
  stage(1, 32);
  asm volatile("s_waitcnt vmcnt(2)" ::: "memory");
  __builtin_amdgcn_s_barrier();
  __builtin_amdgcn_sched_barrier(0);

  for (int t = 0; t < nk; ++t) {
    const int cur = t % 3;
    if (t + 2 < nk) stage((t + 2) % 3, (t + 2) << 5);

    bf16x8 af[2], bfr[2];
#pragma unroll
    for (int mi = 0; mi < 2; ++mi)
      af[mi] = *(const bf16x8*)&As[cur][(wr * 32 + mi * 16 + l15) * 32 + l4 * 8];
#pragma unroll
    for (int ni = 0; ni < 2; ++ni)
      bfr[ni] = *(const bf16x8*)&Bs[cur][(wc * 32 + ni * 16 + l15) * 32 + l4 * 8];
#pragma unroll
    for (int mi = 0; mi < 2; ++mi)
#pragma unroll
      for (int ni = 0; ni < 2; ++ni)
        acc[mi][ni] = __builtin_amdgcn_mfma_f32_16x16x32_bf16(af[mi], bfr[ni], acc[mi][ni], 0, 0, 0);

    if (t + 2 < nk) {
      asm volatile("s_waitcnt vmcnt(2)" ::: "memory");
    } else if (t + 1 < nk) {
      asm volatile("s_waitcnt vmcnt(0)" ::: "memory");
    } else {
      break;
    }
    __builtin_amdgcn_s_barrier();
    __builtin_amdgcn_sched_barrier(0);
  }

  const int r0 = by * 64 + wr * 32, c0 = bx * 64 + wc * 32;
#pragma unroll
  for (int ni = 0; ni < 2; ++ni)
#pragma unroll
    for (int mi = 0; mi < 2; ++mi)
#pragma unroll
      for (int r = 0; r < 4; ++r)
        epi_store<EPI>(outp, bias, res, r0 + mi * 16 + l4 * 4 + r,
                       c0 + ni * 16 + l15, N, acc[mi][ni][r]);
}

// ---------------- Flash attention: 32x32 MFMA, 4 waves x 32 q-rows, KVBLK=64 --
// Swapped QK^T (A=K rows, B=Q^T): lane holds S^T[32 keys][q=lane&31] in regs.
// Softmax fully in-lane + 1 shfl_xor(32). P -> PV A-fragment via 16 packbf2 +
// 8 v_permlane32_swap_b32 (pure VALU, no bpermute). Defer-max (exp2 domain),
// T14 async K/V stage double-buffered, T5 setprio around MFMA clusters.
__global__ __launch_bounds__(256) void attn_fwd(
    const bf16_t* __restrict__ Q, int qs,
    const bf16_t* __restrict__ K, const bf16_t* __restrict__ V, int kvs,
    bf16_t* __restrict__ O, int os, int nq, int nk)
{
  __shared__ bf16_t Ks[2][64][72];
  __shared__ bf16_t Vt[2][64][72];   // Vt[d][key]

  const int tid = threadIdx.x, lane = tid & 63, wv = tid >> 6;
  const int l31 = lane & 31, hi = lane >> 5;
  const int h = blockIdx.y, bz = blockIdx.z;
  const size_t qrow0 = (size_t)bz * nq + (size_t)blockIdx.x * 128 + wv * 32;
  const bf16_t* Qb = Q + qrow0 * qs + h * 64;
  const bf16_t* Kb = K + (size_t)bz * nk * kvs + h * 64;
  const bf16_t* Vb = V + (size_t)bz * nk * kvs + h * 64;
  bf16_t* Ob = O + qrow0 * os + h * 64;

  // Q as B-operand: lane holds Q[q=l31][dk = c*16 + hi*8 + j]
  bf16x8 qa[4];
#pragma unroll
  for (int c = 0; c < 4; ++c)
    qa[c] = *(const bf16x8*)(Qb + (size_t)l31 * qs + c * 16 + hi * 8);

  // staging (256 threads): K rows, V gather-transpose
  const int krow = tid >> 2, kcol = (tid & 3) * 16;
  const int vd = tid & 63, vkb = tid >> 6;

  u16x8 kreg[2], vreg[2];
  auto load_tile = [&](int kt) {
#pragma unroll
    for (int i = 0; i < 2; ++i)
      kreg[i] = *(const u16x8*)(Kb + (size_t)(kt * 64 + krow) * kvs + kcol + i * 8);
#pragma unroll
    for (int i = 0; i < 2; ++i) {
      u16x8 t;
#pragma unroll
      for (int j = 0; j < 8; ++j)
        t[j] = *(const u16*)(Vb + (size_t)(kt * 64 + vkb * 16 + i * 8 + j) * kvs + vd);
      vreg[i] = t;
    }
  };
  auto store_tile = [&](int buf) {
#pragma unroll
    for (int i = 0; i < 2; ++i)
      *(u16x8*)&Ks[buf][krow][kcol + i * 8] = kreg[i];
#pragma unroll
    for (int i = 0; i < 2; ++i)
      *(u16x8*)&Vt[buf][vd][vkb * 16 + i * 8] = vreg[i];
  };

  float m_run2 = -1e30f, l_run = 0.f;  // stats for q = l31 (exp2 domain)
  f32x16 acc[2] = {};                  // acc[dblk][r]: O[q=(r&3)+8(r>>2)+4hi][d=dblk*32+l31]

  const int ntiles = nk >> 6;
  load_tile(0);
  store_tile(0);
  __syncthreads();

  for (int kt = 0; kt < ntiles; ++kt) {
    const int cur = kt & 1;
    const bool pre = (kt + 1 < ntiles);
    if (pre) load_tile(kt + 1);   // HBM latency hides under compute

    // S^T[key][q]: s[kb][r] = S[key = kb*32 + (r&3)+8(r>>2)+4hi][q = l31]
    f32x16 s[2] = {};
    __builtin_amdgcn_s_setprio(1);
#pragma unroll
    for (int kb = 0; kb < 2; ++kb)
#pragma unroll
      for (int c = 0; c < 4; ++c) {
        bf16x8 kf = *(const bf16x8*)&Ks[cur][kb * 32 + l31][c * 16 + hi * 8];
        s[kb] = __builtin_amdgcn_mfma_f32_32x32x16_bf16(kf, qa[c], s[kb], 0, 0, 0);
      }
    __builtin_amdgcn_s_setprio(0);

    // row max (32 in-lane values + partner combine)
    float smax = s[0][0];
#pragma unroll
    for (int kb = 0; kb < 2; ++kb)
#pragma unroll
      for (int r = 0; r < 16; ++r) smax = fmaxf(smax, s[kb][r]);
    smax *= ATT_SC2;
    smax = fmaxf(smax, __shfl_xor(smax, 32));

    // defer-max rescale (rare after first tile)
    if (!__all(smax <= m_run2 + 11.0f)) {
      const float mn = fmaxf(m_run2, smax);
      const float esc = exp2f(m_run2 - mn);
      m_run2 = mn;
      l_run *= esc;
#pragma unroll
      for (int r = 0; r < 16; ++r) {
        int q = (r & 3) + 8 * (r >> 2) + 4 * hi;
        float eq = __shfl(esc, q);
        acc[0][r] *= eq;
        acc[1][r] *= eq;
      }
    }

    // P = 2^(s*SC2 - m2); pack + permlane32_swap into PV A-fragments
    float psum = 0.f;
    u32x4 paw[2][2];   // [kb][h] -> 4 words of bf16x8 A-frag
#pragma unroll
    for (int kb = 0; kb < 2; ++kb) {
      float pv[16];
#pragma unroll
      for (int r = 0; r < 16; ++r) {
        pv[r] = exp2f(s[kb][r] * ATT_SC2 - m_run2);
        psum += pv[r];
      }
#pragma unroll
      for (int h2 = 0; h2 < 2; ++h2) {
        u32 a0 = packbf2(pv[h2 * 8 + 0], pv[h2 * 8 + 1]);
        u32 a1 = packbf2(pv[h2 * 8 + 2], pv[h2 * 8 + 3]);
        u32 a2 = packbf2(pv[h2 * 8 + 4], pv[h2 * 8 + 5]);
        u32 a3 = packbf2(pv[h2 * 8 + 6], pv[h2 * 8 + 7]);
        asm volatile("v_permlane32_swap_b32 %0, %1" : "+v"(a0), "+v"(a2));
        asm volatile("v_permlane32_swap_b32 %0, %1" : "+v"(a1), "+v"(a3));
        paw[kb][h2][0] = a0; paw[kb][h2][1] = a1;
        paw[kb][h2][2] = a2; paw[kb][h2][3] = a3;
      }
    }
    psum += __shfl_xor(psum, 32);
    l_run += psum;

    // O += P V
    __builtin_amdgcn_s_setprio(1);
#pragma unroll
    for (int kb = 0; kb < 2; ++kb)
#pragma unroll
      for (int h2 = 0; h2 < 2; ++h2) {
        union { u32x4 w; bf16x8 v; } pu;
        pu.w = paw[kb][h2];
#pragma unroll
        for (int dblk = 0; dblk < 2; ++dblk) {
          bf16x8 vb = *(const bf16x8*)&Vt[cur][dblk * 32 + l31][kb * 32 + h2 * 16 + hi * 8];
          acc[dblk] = __builtin_amdgcn_mfma_f32_32x32x16_bf16(pu.v, vb, acc[dblk], 0, 0, 0);
        }
      }
    __builtin_amdgcn_s_setprio(0);

    if (pre) store_tile(cur ^ 1);
    __syncthreads();
  }

#pragma unroll
  for (int r = 0; r < 16; ++r) {
    int q = (r & 3) + 8 * (r >> 2) + 4 * hi;
    float lq = __shfl(l_run, q);
    float inv = 1.f / lq;
#pragma unroll
    for (int dblk = 0; dblk < 2; ++dblk)
      Ob[(size_t)q * os + dblk * 32 + l31] = (bf16_t)(acc[dblk][r] * inv);
  }
}

// ---------------- LayerNorm: fp32 in, bf16 out, dim=1024 ----------------
__global__ __launch_bounds__(256) void layernorm_f32_bf16(
    const float* __restrict__ x, const float* __restrict__ g, const float* __restrict__ b,
    bf16_t* __restrict__ out)
{
  const int row = blockIdx.x, tid = threadIdx.x;
  const float4 v = ((const float4*)(x + (size_t)row * 1024))[tid];
  float s = v.x + v.y + v.z + v.w;
  float s2 = v.x * v.x + v.y * v.y + v.z * v.z + v.w * v.w;
#pragma unroll
  for (int off = 32; off > 0; off >>= 1) {
    s += __shfl_down(s, off);
    s2 += __shfl_down(s2, off);
  }
  __shared__ float ps[4], ps2[4];
  const int lane = tid & 63, wave = tid >> 6;
  if (lane == 0) { ps[wave] = s; ps2[wave] = s2; }
  __syncthreads();
  s = ps[0] + ps[1] + ps[2] + ps[3];
  s2 = ps2[0] + ps2[1] + ps2[2] + ps2[3];
  const float mu = s * (1.f / 1024.f);
  const float var = s2 * (1.f / 1024.f) - mu * mu;
  const float rstd = rsqrtf(var + 1e-5f);
  const float4 gv = ((const float4*)g)[tid];
  const float4 bv = ((const float4*)b)[tid];
  bf16x4 o;
  o[0] = (bf16_t)((v.x - mu) * rstd * gv.x + bv.x);
  o[1] = (bf16_t)((v.y - mu) * rstd * gv.y + bv.y);
  o[2] = (bf16_t)((v.z - mu) * rstd * gv.z + bv.z);
  o[3] = (bf16_t)((v.w - mu) * rstd * gv.w + bv.w);
  *(bf16x4*)(out + (size_t)row * 1024 + tid * 4) = o;
}

// ---------------- weight transpose fp32[K,N] -> bf16[N,K], per-layer in grid.z ----------------
__global__ void transpose_to_bf16(const float* __restrict__ src, bf16_t* __restrict__ dst, int K, int N)
{
  __shared__ float tile[32][33];
  const size_t loff = (size_t)blockIdx.z * K * N;
  src += loff; dst += loff;
  const int k0 = blockIdx.y * 32, n0 = blockIdx.x * 32;
  const int tx = threadIdx.x, ty = threadIdx.y;
#pragma unroll
  for (int i = ty; i < 32; i += 8)
    tile[i][tx] = src[(size_t)(k0 + i) * N + n0 + tx];
  __syncthreads();
#pragma unroll
  for (int i = ty; i < 32; i += 8)
    dst[(size_t)(n0 + i) * K + k0 + tx] = (bf16_t)tile[tx][i];
}

__global__ void f32_to_bf16(const float* __restrict__ src, bf16_t* __restrict__ dst, int n4)
{
  int i = blockIdx.x * blockDim.x + threadIdx.x;
  if (i < n4) {
    float4 v = ((const float4*)src)[i];
    bf16x4 o;
    o[0] = (bf16_t)v.x; o[1] = (bf16_t)v.y; o[2] = (bf16_t)v.z; o[3] = (bf16_t)v.w;
    ((bf16x4*)dst)[i] = o;
  }
}

__global__ void copy_f32(const float* __restrict__ src, float* __restrict__ dst, int n4)
{
  int i = blockIdx.x * blockDim.x + threadIdx.x;
  if (i < n4) ((float4*)dst)[i] = ((const float4*)src)[i];
}

extern "C" void kernel_launch(void* const* d_in, const int* in_sizes, int n_in,
                              void* d_out, int out_size, void* d_ws, size_t ws_size,
                              hipStream_t stream)
{
  const float* x      = (const float*)d_in[0];
  const float* ctx    = (const float*)d_in[1];
  const float* ln1_g  = (const float*)d_in[2];
  const float* ln1_b  = (const float*)d_in[3];
  const float* w_qkv  = (const float*)d_in[4];
  const float* w_sa_o = (const float*)d_in[5];
  const float* b_sa_o = (const float*)d_in[6];
  const float* ln2_g  = (const float*)d_in[7];
  const float* ln2_b  = (const float*)d_in[8];
  const float* w_q    = (const float*)d_in[9];
  const float* w_kv   = (const float*)d_in[10];
  const float* w_ca_o = (const float*)d_in[11];
  const float* b_ca_o = (const float*)d_in[12];
  const float* ln3_g  = (const float*)d_in[13];
  const float* ln3_b  = (const float*)d_in[14];
  const float* w_ff1  = (const float*)d_in[15];
  const float* b_ff1  = (const float*)d_in[16];
  const float* w_ff2  = (const float*)d_in[17];
  const float* b_ff2  = (const float*)d_in[18];

  char* p = (char*)d_ws;
  auto alloc = [&](size_t bytes) { char* r = p; p += (bytes + 255) & ~(size_t)255; return r; };
  bf16_t* wqkv_t = (bf16_t*)alloc((size_t)NDEPTH * 3072 * 1024 * 2);
  bf16_t* wsao_t = (bf16_t*)alloc((size_t)NDEPTH * 1024 * 1024 * 2);
  bf16_t* wq_t   = (bf16_t*)alloc((size_t)NDEPTH * 1024 * 1024 * 2);
  bf16_t* wkv_t  = (bf16_t*)alloc((size_t)NDEPTH * 2048 * 768 * 2);
  bf16_t* wcao_t = (bf16_t*)alloc((size_t)NDEPTH * 1024 * 1024 * 2);
  bf16_t* wff1_t = (bf16_t*)alloc((size_t)NDEPTH * 4096 * 1024 * 2);
  bf16_t* wff2_t = (bf16_t*)alloc((size_t)NDEPTH * 1024 * 4096 * 2);
  bf16_t* ctxb   = (bf16_t*)alloc((size_t)NCTX * CTXD * 2);
  float*  xbuf   = (float*)alloc((size_t)NTOK * DIM * 4);
  bf16_t* lnbuf  = (bf16_t*)alloc((size_t)NTOK * DIM * 2);    // also attention out
  bf16_t* bigbuf = (bf16_t*)alloc((size_t)NTOK * 4096 * 2);   // qkv / ff1 out
  bf16_t* qbuf   = (bf16_t*)alloc((size_t)NTOK * DIM * 2);
  bf16_t* kvbuf  = (bf16_t*)alloc((size_t)NCTX * 2048 * 2);
  if ((size_t)(p - (char*)d_ws) > ws_size) return;  // workspace too small: fail loudly

  dim3 tb(32, 8);
  transpose_to_bf16<<<dim3(3072 / 32, 1024 / 32, NDEPTH), tb, 0, stream>>>(w_qkv, wqkv_t, 1024, 3072);
  transpose_to_bf16<<<dim3(1024 / 32, 1024 / 32, NDEPTH), tb, 0, stream>>>(w_sa_o, wsao_t, 1024, 1024);
  transpose_to_bf16<<<dim3(1024 / 32, 1024 / 32, NDEPTH), tb, 0, stream>>>(w_q, wq_t, 1024, 1024);
  transpose_to_bf16<<<dim3(2048 / 32, 768 / 32, NDEPTH), tb, 0, stream>>>(w_kv, wkv_t, 768, 2048);
  transpose_to_bf16<<<dim3(1024 / 32, 1024 / 32, NDEPTH), tb, 0, stream>>>(w_ca_o, wcao_t, 1024, 1024);
  transpose_to_bf16<<<dim3(4096 / 32, 1024 / 32, NDEPTH), tb, 0, stream>>>(w_ff1, wff1_t, 1024, 4096);
  transpose_to_bf16<<<dim3(1024 / 32, 4096 / 32, NDEPTH), tb, 0, stream>>>(w_ff2, wff2_t, 4096, 1024);
  f32_to_bf16<<<(NCTX * CTXD / 4 + 255) / 256, 256, 0, stream>>>(ctx, ctxb, NCTX * CTXD / 4);
  copy_f32<<<(NTOK * DIM / 4 + 255) / 256, 256, 0, stream>>>(x, xbuf, NTOK * DIM / 4);

  for (int i = 0; i < NDEPTH; ++i) {
    // ---- self-attention ----
    layernorm_f32_bf16<<<NTOK, 256, 0, stream>>>(xbuf, ln1_g + i * DIM, ln1_b + i * DIM, lnbuf);
    gemm_bf16<0><<<dim3(3072 / 128, NTOK / 128), 512, 0, stream>>>(
        lnbuf, wqkv_t + (size_t)i * 3072 * 1024, nullptr, nullptr, bigbuf, NTOK, 3072, 1024);
    attn_fwd<<<dim3(2048 / 128, NHEADS, 2), 256, 0, stream>>>(
        bigbuf, 3072, bigbuf + 1024, bigbuf + 2048, 3072, lnbuf, 1024, 2048, 2048);
    gemm64_bf16<3><<<dim3(1024 / 64, NTOK / 64), 256, 0, stream>>>(
        lnbuf, wsao_t + (size_t)i * 1024 * 1024, b_sa_o + i * DIM, xbuf, xbuf, NTOK, 1024, 1024);
    // ---- cross-attention ----
    layernorm_f32_bf16<<<NTOK, 256, 0, stream>>>(xbuf, ln2_g + i * DIM, ln2_b + i * DIM, lnbuf);
    gemm64_bf16<0><<<dim3(1024 / 64, NTOK / 64), 256, 0, stream>>>(
        lnbuf, wq_t + (size_t)i * 1024 * 1024, nullptr, nullptr, qbuf, NTOK, 1024, 1024);
    gemm64_bf16<0><<<dim3(2048 / 64, NCTX / 64), 256, 0, stream>>>(
        ctxb, wkv_t + (size_t)i * 2048 * 768, nullptr, nullptr, kvbuf, NCTX, 2048, 768);
    attn_fwd<<<dim3(2048 / 128, NHEADS, 2), 256, 0, stream>>>(
        qbuf, 1024, kvbuf, kvbuf + 1024, 2048, lnbuf, 1024, 2048, 1024);
    gemm64_bf16<3><<<dim3(1024 / 64, NTOK / 64), 256, 0, stream>>>(
        lnbuf, wcao_t + (size_t)i * 1024 * 1024, b_ca_o + i * DIM, xbuf, xbuf, NTOK, 1024, 1024);
    // ---- feed-forward ----
    layernorm_f32_bf16<<<NTOK, 256, 0, stream>>>(xbuf, ln3_g + i * DIM, ln3_b + i * DIM, lnbuf);
    gemm_bf16<2><<<dim3(4096 / 128, NTOK / 128), 512, 0, stream>>>(
        lnbuf, wff1_t + (size_t)i * 4096 * 1024, b_ff1 + i * MLP_DIM, nullptr, bigbuf, NTOK, 4096, 1024);
    gemm64_bf16<3><<<dim3(1024 / 64, NTOK / 64), 256, 0, stream>>>(
        bigbuf, wff2_t + (size_t)i * 1024 * 4096, b_ff2 + i * DIM, xbuf, xbuf, NTOK, 1024, 4096);
  }
  copy_f32<<<(NTOK * DIM / 4 + 255) / 256, 256, 0, stream>>>(xbuf, (float*)d_out, NTOK * DIM / 4);
}